// Round 10
// baseline (167.030 us; speedup 1.0000x reference)
//
#include <hip/hip_runtime.h>

typedef _Float16 f16;
typedef __attribute__((ext_vector_type(8))) _Float16 f16x8;
typedef __attribute__((ext_vector_type(4))) float f32x4;
typedef __attribute__((ext_vector_type(4))) int i32x4;

// padded spatial layout: [b][y][x][128ch], y,x in 0..129, zero halo.

// conv weight pack: [ky][cc][nb][kx][64 o][4 g][8]; slot g holds chunk g^((o>>1)&3)
__device__ __forceinline__ void pack_conv(const float* __restrict__ src, f16* __restrict__ dst,
                                          long idx, int C) {
  int ci3 = idx & 7;
  int g = (idx >> 3) & 3;
  long t = idx >> 5;
  int o = (int)(t & 63); t >>= 6;
  int kx = (int)(t % 3); t /= 3;
  int nb = (int)(t & 1); t >>= 1;
  int nkc = C >> 5;
  int cc = (int)(t % nkc);
  int ky = (int)(t / nkc);
  int og = nb * 64 + o;
  int c = (cc << 5) + ((g ^ ((o >> 1) & 3)) << 3) + ci3;
  dst[idx] = (f16)src[(((size_t)og * C + c) * 3 + ky) * 3 + kx];
}

__device__ __forceinline__ void halo_zero(f16* __restrict__ buf, long e) {
  int c = (int)(e & 127);
  long t = e >> 7;
  int b = (int)(t / 516);
  int p = (int)(t % 516);
  int y, x;
  if (p < 130)      { y = 0;   x = p; }
  else if (p < 260) { y = 129; x = p - 130; }
  else if (p < 388) { x = 0;   y = p - 259; }
  else              { x = 129; y = p - 387; }
  buf[((size_t)(b * 130 + y) * 130 + x) * 128 + c] = (f16)0.f;
}

// ---- init: NCHW->padded-NHWC (xP, refP) + weight packing + halo zeroing ----
__global__ __launch_bounds__(256) void init_k(const float* __restrict__ x, const float* __restrict__ ref,
                                              const float* __restrict__ w1, const float* __restrict__ w2,
                                              const float* __restrict__ woff, const float* __restrict__ wdef,
                                              f16* __restrict__ W1p, f16* __restrict__ W2p,
                                              f16* __restrict__ Woffp, f16* __restrict__ Wdefp,
                                              f16* __restrict__ xP, f16* __restrict__ refP,
                                              f16* __restrict__ est1, f16* __restrict__ est2) {
  __shared__ __align__(16) f16 T[64][40];
  int tid = threadIdx.x;
  if (blockIdx.x < 4096) {  // transpose
    int bi = blockIdx.x;
    int row = bi & 255, wseg = (bi >> 8) & 1, chunk = bi >> 9;
    int b = row >> 7, h = row & 127;
    int w0 = wseg * 64;
    const float* src = (chunk < 4) ? x : ref;
    f16* dstp = (chunk < 4) ? xP : refP;
    int c0 = (chunk & 3) * 32;
#pragma unroll
    for (int i = 0; i < 2; ++i) {
      int idx = tid + i * 256;
      int c = idx >> 4, g = idx & 15;
      const float4 v = *(const float4*)(src + (((size_t)(b * 128 + c0 + c)) * 128 + h) * 128 + w0 + g * 4);
      T[g * 4 + 0][c] = (f16)v.x;
      T[g * 4 + 1][c] = (f16)v.y;
      T[g * 4 + 2][c] = (f16)v.z;
      T[g * 4 + 3][c] = (f16)v.w;
    }
    __syncthreads();
    int w = tid >> 2, g = tid & 3;
    f16x8 o = *(const f16x8*)&T[w][g * 8];
    *(f16x8*)(dstp + ((size_t)(b * 130 + h + 1) * 130 + w0 + w + 1) * 128 + c0 + g * 8) = o;
    return;
  }
  long idx = (long)(blockIdx.x - 4096) * 256 + tid;
  if (idx < 294912) { pack_conv(w1, W1p, idx, 256); return; }
  idx -= 294912;
  if (idx < 147456) { pack_conv(w2, W2p, idx, 128); return; }
  idx -= 147456;
  if (idx < 36864) {  // Woffp: [ky][cc][kx][32 o][4 g][8], o>=18 zero
    int ci3 = (int)(idx & 7);
    int g = (int)((idx >> 3) & 3);
    int o = (int)((idx >> 5) & 31);
    int t2 = (int)(idx >> 10);
    int kx = t2 % 3; t2 /= 3;
    int cc = t2 & 3, ky = t2 >> 2;
    int c = (cc << 5) + ((g ^ ((o >> 1) & 3)) << 3) + ci3;
    Woffp[idx] = (o < 18) ? (f16)woff[(((size_t)o * 128 + c) * 3 + ky) * 3 + kx] : (f16)0.f;
    return;
  }
  idx -= 36864;
  if (idx < 147456) {  // Wdefp: [t][cc][ofr][lane][8] lane-linear A-frags
    int j = (int)(idx & 7);
    int ln = (int)((idx >> 3) & 63);
    int ofr = (int)((idx >> 9) & 7);
    int cc = (int)((idx >> 12) & 3);
    int t = (int)(idx >> 14);
    int o = ofr * 16 + (ln & 15);
    int c = cc * 32 + (ln >> 4) * 8 + j;
    Wdefp[idx] = (f16)wdef[(((size_t)o * 128 + c) * 3 + t / 3) * 3 + t % 3];
    return;
  }
  idx -= 147456;
  if (idx < 132096) { halo_zero(xP, idx); return; }
  idx -= 132096;
  if (idx < 132096) { halo_zero(refP, idx); return; }
  idx -= 132096;
  if (idx < 132096) { halo_zero(est1, idx); return; }
  idx -= 132096;
  if (idx < 132096) halo_zero(est2, idx);
}

// ---- implicit-GEMM 3x3 conv: M=128 (full row), N=64, BK=32, 4 waves ----
// NEW (R10): B-fragments loaded DIRECT from global (weights are L2-resident,
// shared by all 512 blocks) into double-buffered registers, one stage ahead.
// Only A flows through LDS (3-buf, 1 barrier/stage). LDS traffic -60%; B's
// ingestion moves to the otherwise-idle L2 pipe; Bs ds_write leaves the
// barrier-critical path. s-loop unrolled x2 so bfA/bfB indices are static.
// XCD swizzle: blockIdx%8 = XCD owns a contiguous 32-row band.
template <int NKC>
__global__ __launch_bounds__(256, 2) void conv_k(const f16* __restrict__ src0,
                                                 const f16* __restrict__ src1,
                                                 const f16* __restrict__ Wp,
                                                 f16* __restrict__ dst) {
  constexpr int S = 3 * NKC;  // 24 or 12 (even)
  const int j = blockIdx.x;         // 0..511
  const int xcd = j & 7, ji = j >> 3;
  const int row = xcd * 32 + (ji & 31);  // XCD k: rows [32k, 32k+32)
  const int nb = ji >> 5;
  const int b = row >> 7, h = row & 127;
  __shared__ __align__(16) f16 As[3][130][32];  // 24.4 KB total LDS
  const int tid = threadIdx.x;
  const int lane = tid & 63, wave = tid >> 6;
  const int l16 = lane & 15, quad = lane >> 4;
  const int wmB = wave * 32;  // wave tile: 32 px x 64 o
  f32x4 acc[2][4] = {};

  i32x4 ra0, ra1, ra2;  // A staging regs (next stage in flight)

  auto loadA = [&](int s) {
    int ky = s / NKC, cc = s % NKC;
    const f16* sp = (NKC == 8 && cc >= 4) ? src1 : src0;
    int c0 = (NKC == 8 ? (cc & 3) : cc) * 32;
    const f16* abase = sp + ((size_t)(b * 130 + h + ky) * 130) * 128 + c0;
    {
      int ch = tid;
      int xx = ch >> 2, g = ch & 3;
      ra0 = *(const i32x4*)(abase + (size_t)xx * 128 + ((g ^ ((xx >> 1) & 3)) << 3));
    }
    {
      int ch = 256 + tid;
      int xx = ch >> 2, g = ch & 3;
      ra1 = *(const i32x4*)(abase + (size_t)xx * 128 + ((g ^ ((xx >> 1) & 3)) << 3));
    }
    if (tid < 8) {
      int ch = 512 + tid;
      int xx = ch >> 2, g = ch & 3;
      ra2 = *(const i32x4*)(abase + (size_t)xx * 128 + ((g ^ ((xx >> 1) & 3)) << 3));
    }
  };
  auto writeA = [&](int buf) {
    *(i32x4*)((char*)&As[buf][0][0] + tid * 16) = ra0;
    *(i32x4*)((char*)&As[buf][0][0] + (256 + tid) * 16) = ra1;
    if (tid < 8)
      *(i32x4*)((char*)&As[buf][0][0] + (512 + tid) * 16) = ra2;
  };
  auto loadB = [&](int s, f16x8 (&bf)[3][4]) {  // 12 coalesced 16B loads/thread
    int ky = s / NKC, cc = s % NKC;
    const f16* bbase = Wp + (size_t)((ky * NKC + cc) * 2 + nb) * (3 * 64 * 32);
#pragma unroll
    for (int kx = 0; kx < 3; ++kx)
#pragma unroll
      for (int j2 = 0; j2 < 4; ++j2) {
        int o = j2 * 16 + l16;
        bf[kx][j2] = *(const f16x8*)(bbase + kx * (64 * 32) + o * 32 +
                                     ((quad ^ ((o >> 1) & 3)) << 3));
      }
  };
  auto compute = [&](int buf, f16x8 (&bf)[3][4]) {
#pragma unroll
    for (int kx = 0; kx < 3; ++kx)
#pragma unroll
      for (int i = 0; i < 2; ++i) {
        int xx = wmB + i * 16 + l16 + kx;
        f16x8 a = *(const f16x8*)&As[buf][xx][(quad ^ ((xx >> 1) & 3)) << 3];
#pragma unroll
        for (int j2 = 0; j2 < 4; ++j2)
          acc[i][j2] = __builtin_amdgcn_mfma_f32_16x16x32_f16(a, bf[kx][j2], acc[i][j2], 0, 0, 0);
      }
  };

  f16x8 bfA[3][4], bfB[3][4];  // B double-buffer (static-indexed via x2 unroll)
  loadA(0); writeA(0);
  loadA(1);
  loadB(0, bfA);
  __syncthreads();
  for (int s = 0; s < S; s += 2) {
    // even stage s: compute with bfA; bfB(s+1) goes in flight first
    if (s + 1 < S) loadB(s + 1, bfB);
    compute(s % 3, bfA);
    if (s + 1 < S) writeA((s + 1) % 3);  // buf's last readers passed 2 barriers ago
    if (s + 2 < S) loadA(s + 2);
    __syncthreads();
    // odd stage s+1: compute with bfB
    if (s + 1 < S) {
      if (s + 2 < S) loadB(s + 2, bfA);
      compute((s + 1) % 3, bfB);
      if (s + 2 < S) writeA((s + 2) % 3);
      if (s + 3 < S) loadA(s + 3);
      __syncthreads();
    }
  }
#pragma unroll
  for (int i = 0; i < 2; ++i)
#pragma unroll
    for (int j2 = 0; j2 < 4; ++j2) {
      int o = nb * 64 + j2 * 16 + l16;
#pragma unroll
      for (int rr = 0; rr < 4; ++rr) {
        int m = wmB + i * 16 + quad * 4 + rr;
        float v = fmaxf(acc[i][j2][rr], 0.f);
        dst[((size_t)(b * 130 + h + 1) * 130 + m + 1) * 128 + o] = (f16)v;
      }
    }
}

// ---- deform (merged offset conv): R9 version unchanged ----
__global__ __launch_bounds__(256, 2) void deform_k(const f16* __restrict__ refP,
                                                   const f16* __restrict__ est2,
                                                   const f16* __restrict__ Woffp,
                                                   const f16* __restrict__ Wdefp,
                                                   float* __restrict__ out) {
  const int j = blockIdx.x;  // 0..511
  const int xcd = j & 7, ji = j >> 3;
  const int row = xcd * 32 + (ji & 31);  // XCD band: gathers stay in 4MB L2
  const int tile = ji >> 5;
  const int b = row >> 7, h = row & 127;
  __shared__ __align__(16) char smem[32768];
  __shared__ __align__(16) float offs[64][32];  // 8 KB, phase A out -> phase B in
  __shared__ int4 meta[9][64];                  // 9 KB
  f16 (*Ss)[64][128] = (f16(*)[64][128])smem;
  f16 (*As3)[66][32] = (f16(*)[66][32])smem;                  // 3 x 4224 B
  f16 (*Bs3)[3][32][32] = (f16(*)[3][32][32])(smem + 12672);  // 3 x 6144 B
  const int tid = threadIdx.x;
  const int lane = tid & 63, wave = tid >> 6;
  const int l16 = lane & 15, quad = lane >> 4;
  const int x0 = tile * 64;  // padded-col window base: cols x0 .. x0+65

  // ---- phase A: offset mini-conv, 12 stages (ky 0..2 x cc 0..3) ----
  {
    i32x4 ra0, ra1, rb0, rb1;
    auto sl = [&](int s) {
      int ky = s >> 2, cc = s & 3;
      const f16* abase = est2 + (((size_t)(b * 130 + h + ky)) * 130 + x0) * 128 + cc * 32;
      {
        int ch = tid;  // 264 chunks of 16B total (66 px x 32 ch)
        int xx = ch >> 2, g = ch & 3;
        ra0 = *(const i32x4*)(abase + (size_t)xx * 128 + ((g ^ ((xx >> 1) & 3)) << 3));
      }
      if (tid < 8) {
        int ch = 256 + tid;
        int xx = ch >> 2, g = ch & 3;
        ra1 = *(const i32x4*)(abase + (size_t)xx * 128 + ((g ^ ((xx >> 1) & 3)) << 3));
      }
      const f16* bbase = Woffp + (size_t)(ky * 4 + cc) * (3 * 32 * 32);
      rb0 = *(const i32x4*)(bbase + (size_t)tid * 8);
      if (tid < 128) rb1 = *(const i32x4*)(bbase + (size_t)(256 + tid) * 8);
    };
    auto sw = [&](int buf) {
      *(i32x4*)((char*)&As3[buf][0][0] + tid * 16) = ra0;
      if (tid < 8)
        *(i32x4*)((char*)&As3[buf][0][0] + (256 + tid) * 16) = ra1;
      *(i32x4*)((char*)&Bs3[buf][0][0][0] + tid * 16) = rb0;
      if (tid < 128)
        *(i32x4*)((char*)&Bs3[buf][0][0][0] + (256 + tid) * 16) = rb1;
    };
    f32x4 oacc[2] = {};
    sl(0); sw(0); sl(1);
    __syncthreads();
    for (int s = 0; s < 12; ++s) {
      const int buf = s % 3;
#pragma unroll
      for (int kx = 0; kx < 3; ++kx) {
        f16x8 bf[2];
#pragma unroll
        for (int j2 = 0; j2 < 2; ++j2) {
          int o = j2 * 16 + l16;
          bf[j2] = *(const f16x8*)&Bs3[buf][kx][o][(quad ^ ((o >> 1) & 3)) << 3];
        }
        int xx = wave * 16 + l16 + kx;
        f16x8 a = *(const f16x8*)&As3[buf][xx][(quad ^ ((xx >> 1) & 3)) << 3];
#pragma unroll
        for (int j2 = 0; j2 < 2; ++j2)
          oacc[j2] = __builtin_amdgcn_mfma_f32_16x16x32_f16(a, bf[j2], oacc[j2], 0, 0, 0);
      }
      if (s + 1 < 12) sw((s + 1) % 3);
      if (s + 2 < 12) sl(s + 2);
      __syncthreads();
    }
#pragma unroll
    for (int j2 = 0; j2 < 2; ++j2)
#pragma unroll
      for (int rr = 0; rr < 4; ++rr)
        offs[wave * 16 + quad * 4 + rr][j2 * 16 + l16] = oacc[j2][rr];
  }
  __syncthreads();  // offs ready; As3/Bs3 dead from here (Ss may overwrite)

  // ---- phase B: meta from offs ----
  for (int e = tid; e < 576; e += 256) {
    int t = e >> 6, p = e & 63;
    int wg = tile * 64 + p;
    float dy = offs[p][2 * t], dx = offs[p][2 * t + 1];
    float py = (float)(h + t / 3 - 1) + dy;
    float px = (float)(wg + t % 3 - 1) + dx;
    float fy = floorf(py), fx = floorf(px);
    meta[t][p] = make_int4((int)fy, (int)fx, __float_as_int(py - fy), __float_as_int(px - fx));
  }

  const int sp_p = tid >> 2, sp_cg = tid & 3;
  f16x8 v00[4], v01[4], v10[4], v11[4];  // gather corners (one tap in flight)
  f16 h00, h01, h10, h11;

  auto sample_issue = [&](int t) {
    int4 mt = meta[t][sp_p];
    int yp = mt.x + 1, xp = mt.y + 1;  // padded coords
    float wy = __int_as_float(mt.z), wx = __int_as_float(mt.w);
    bool y0v = (unsigned)yp < 130u, y1v = (unsigned)(yp + 1) < 130u;
    bool x0v = (unsigned)xp < 130u, x1v = (unsigned)(xp + 1) < 130u;
    int cy0 = y0v ? yp : 0, cy1 = y1v ? yp + 1 : 0;
    int cx0 = x0v ? xp : 0, cx1 = x1v ? xp + 1 : 0;
    float u0 = (1.f - wy) * (y0v ? 1.f : 0.f), u1 = wy * (y1v ? 1.f : 0.f);
    float s0 = (1.f - wx) * (x0v ? 1.f : 0.f), s1 = wx * (x1v ? 1.f : 0.f);
    h00 = (f16)(u0 * s0); h01 = (f16)(u0 * s1);
    h10 = (f16)(u1 * s0); h11 = (f16)(u1 * s1);
    const size_t bb = (size_t)b * 130;
    const f16* p00 = refP + ((bb + cy0) * 130 + cx0) * 128 + sp_cg * 32;
    const f16* p01 = refP + ((bb + cy0) * 130 + cx1) * 128 + sp_cg * 32;
    const f16* p10 = refP + ((bb + cy1) * 130 + cx0) * 128 + sp_cg * 32;
    const f16* p11 = refP + ((bb + cy1) * 130 + cx1) * 128 + sp_cg * 32;
#pragma unroll
    for (int q = 0; q < 4; ++q) {
      v00[q] = *(const f16x8*)(p00 + q * 8);
      v01[q] = *(const f16x8*)(p01 + q * 8);
      v10[q] = *(const f16x8*)(p10 + q * 8);
      v11[q] = *(const f16x8*)(p11 + q * 8);
    }
  };
  auto sample_finish = [&](int buf) {
#pragma unroll
    for (int q = 0; q < 4; ++q) {
      f16x8 rb = v00[q] * h00 + v01[q] * h01 + v10[q] * h10 + v11[q] * h11;
      int c = sp_cg * 4 + q;
      *(f16x8*)&Ss[buf][sp_p][(c ^ (sp_p & 7)) << 3] = rb;
    }
  };

  f32x4 acc[2][4] = {};
  f16x8 af0[4][2], af1[4][2];  // double-buffered weight A-frags
  __syncthreads();  // meta ready
  sample_issue(0);
  sample_finish(0);   // tap 0 sampled into Ss[0]
  sample_issue(1);    // tap 1 gathers in flight across the barrier
#pragma unroll
  for (int cc = 0; cc < 4; ++cc)
#pragma unroll
    for (int i = 0; i < 2; ++i)
      af0[cc][i] = *(const f16x8*)(Wdefp +
          ((((size_t)0 * 4 + cc) * 8 + wave * 2 + i) * 64 + lane) * 8);
  __syncthreads();
#pragma unroll
  for (int t = 0; t < 9; ++t) {
    if (t < 8) {
#pragma unroll
      for (int cc = 0; cc < 4; ++cc)
#pragma unroll
        for (int i = 0; i < 2; ++i) {
          f16x8 w = *(const f16x8*)(Wdefp +
              ((((size_t)(t + 1) * 4 + cc) * 8 + wave * 2 + i) * 64 + lane) * 8);
          if (t & 1) af0[cc][i] = w; else af1[cc][i] = w;
        }
    }
    const int buf = t & 1;
    __builtin_amdgcn_s_setprio(1);
#pragma unroll
    for (int cc = 0; cc < 4; ++cc) {
      f16x8 bf[4];
#pragma unroll
      for (int j2 = 0; j2 < 4; ++j2) {
        int p = j2 * 16 + l16;
        bf[j2] = *(const f16x8*)&Ss[buf][p][((cc * 4 + quad) ^ (p & 7)) << 3];
      }
#pragma unroll
      for (int i = 0; i < 2; ++i)
#pragma unroll
        for (int j2 = 0; j2 < 4; ++j2)
          acc[i][j2] = __builtin_amdgcn_mfma_f32_16x16x32_f16(
              (t & 1) ? af1[cc][i] : af0[cc][i], bf[j2], acc[i][j2], 0, 0, 0);
    }
    __builtin_amdgcn_s_setprio(0);
    if (t < 8) sample_finish((t + 1) & 1);
    if (t < 7) sample_issue(t + 2);
    __syncthreads();
  }
#pragma unroll
  for (int i = 0; i < 2; ++i)
#pragma unroll
    for (int rr = 0; rr < 4; ++rr) {
      int o = wave * 32 + i * 16 + quad * 4 + rr;
#pragma unroll
      for (int j2 = 0; j2 < 4; ++j2) {
        int wg = tile * 64 + j2 * 16 + l16;
        out[((size_t)(b * 128 + o) * 128 + h) * 128 + wg] = acc[i][j2][rr];
      }
    }
}

extern "C" void kernel_launch(void* const* d_in, const int* in_sizes, int n_in,
                              void* d_out, int out_size, void* d_ws, size_t ws_size,
                              hipStream_t stream) {
  const float* x = (const float*)d_in[0];
  const float* ref = (const float*)d_in[1];
  const float* w1 = (const float*)d_in[2];
  const float* w2 = (const float*)d_in[3];
  const float* woff = (const float*)d_in[4];
  const float* wdef = (const float*)d_in[5];
  float* out = (float*)d_out;
  char* ws = (char*)d_ws;
  f16* xP = (f16*)(ws + 0);              //  8,652,800
  f16* refP = (f16*)(ws + 8652800);      //  8,652,800
  f16* est1 = (f16*)(ws + 17305600);     //  8,652,800
  f16* est2 = (f16*)(ws + 25958400);     //  8,652,800
  f16* W1p = (f16*)(ws + 34611200);      //    589,824
  f16* W2p = (f16*)(ws + 35201024);      //    294,912
  f16* Woffp = (f16*)(ws + 35495936);    //     73,728
  f16* Wdefp = (f16*)(ws + 35569664);    //    294,912

  init_k<<<dim3(8608), 256, 0, stream>>>(x, ref, w1, w2, woff, wdef,
                                         W1p, W2p, Woffp, Wdefp, xP, refP, est1, est2);
  conv_k<8><<<dim3(512), 256, 0, stream>>>(xP, refP, W1p, est1);
  conv_k<4><<<dim3(512), 256, 0, stream>>>(est1, est1, W2p, est2);
  deform_k<<<dim3(512), 256, 0, stream>>>(refP, est2, Woffp, Wdefp, out);
}

// Round 11
// 155.736 us; speedup vs baseline: 1.0725x; 1.0725x over previous
//
#include <hip/hip_runtime.h>

typedef _Float16 f16;
typedef __attribute__((ext_vector_type(8))) _Float16 f16x8;
typedef __attribute__((ext_vector_type(4))) float f32x4;
typedef __attribute__((ext_vector_type(4))) int i32x4;

// padded spatial layout: [b][y][x][128ch], y,x in 0..129, zero halo.

// conv weight pack: [ky][cc][nb][kx][64 o][4 g][8]; slot g holds chunk g^((o>>1)&3)
__device__ __forceinline__ void pack_conv(const float* __restrict__ src, f16* __restrict__ dst,
                                          long idx, int C) {
  int ci3 = idx & 7;
  int g = (idx >> 3) & 3;
  long t = idx >> 5;
  int o = (int)(t & 63); t >>= 6;
  int kx = (int)(t % 3); t /= 3;
  int nb = (int)(t & 1); t >>= 1;
  int nkc = C >> 5;
  int cc = (int)(t % nkc);
  int ky = (int)(t / nkc);
  int og = nb * 64 + o;
  int c = (cc << 5) + ((g ^ ((o >> 1) & 3)) << 3) + ci3;
  dst[idx] = (f16)src[(((size_t)og * C + c) * 3 + ky) * 3 + kx];
}

__device__ __forceinline__ void halo_zero(f16* __restrict__ buf, long e) {
  int c = (int)(e & 127);
  long t = e >> 7;
  int b = (int)(t / 516);
  int p = (int)(t % 516);
  int y, x;
  if (p < 130)      { y = 0;   x = p; }
  else if (p < 260) { y = 129; x = p - 130; }
  else if (p < 388) { x = 0;   y = p - 259; }
  else              { x = 129; y = p - 387; }
  buf[((size_t)(b * 130 + y) * 130 + x) * 128 + c] = (f16)0.f;
}

// ---- init: NCHW->padded-NHWC (xP, refP) + weight packing + halo zeroing ----
__global__ __launch_bounds__(256) void init_k(const float* __restrict__ x, const float* __restrict__ ref,
                                              const float* __restrict__ w1, const float* __restrict__ w2,
                                              const float* __restrict__ woff, const float* __restrict__ wdef,
                                              f16* __restrict__ W1p, f16* __restrict__ W2p,
                                              f16* __restrict__ Woffp, f16* __restrict__ Wdefp,
                                              f16* __restrict__ xP, f16* __restrict__ refP,
                                              f16* __restrict__ est1, f16* __restrict__ est2) {
  __shared__ __align__(16) f16 T[64][40];
  int tid = threadIdx.x;
  if (blockIdx.x < 4096) {  // transpose
    int bi = blockIdx.x;
    int row = bi & 255, wseg = (bi >> 8) & 1, chunk = bi >> 9;
    int b = row >> 7, h = row & 127;
    int w0 = wseg * 64;
    const float* src = (chunk < 4) ? x : ref;
    f16* dstp = (chunk < 4) ? xP : refP;
    int c0 = (chunk & 3) * 32;
#pragma unroll
    for (int i = 0; i < 2; ++i) {
      int idx = tid + i * 256;
      int c = idx >> 4, g = idx & 15;
      const float4 v = *(const float4*)(src + (((size_t)(b * 128 + c0 + c)) * 128 + h) * 128 + w0 + g * 4);
      T[g * 4 + 0][c] = (f16)v.x;
      T[g * 4 + 1][c] = (f16)v.y;
      T[g * 4 + 2][c] = (f16)v.z;
      T[g * 4 + 3][c] = (f16)v.w;
    }
    __syncthreads();
    int w = tid >> 2, g = tid & 3;
    f16x8 o = *(const f16x8*)&T[w][g * 8];
    *(f16x8*)(dstp + ((size_t)(b * 130 + h + 1) * 130 + w0 + w + 1) * 128 + c0 + g * 8) = o;
    return;
  }
  long idx = (long)(blockIdx.x - 4096) * 256 + tid;
  if (idx < 294912) { pack_conv(w1, W1p, idx, 256); return; }
  idx -= 294912;
  if (idx < 147456) { pack_conv(w2, W2p, idx, 128); return; }
  idx -= 147456;
  if (idx < 36864) {  // Woffp: [ky][cc][kx][32 o][4 g][8], o>=18 zero
    int ci3 = (int)(idx & 7);
    int g = (int)((idx >> 3) & 3);
    int o = (int)((idx >> 5) & 31);
    int t2 = (int)(idx >> 10);
    int kx = t2 % 3; t2 /= 3;
    int cc = t2 & 3, ky = t2 >> 2;
    int c = (cc << 5) + ((g ^ ((o >> 1) & 3)) << 3) + ci3;
    Woffp[idx] = (o < 18) ? (f16)woff[(((size_t)o * 128 + c) * 3 + ky) * 3 + kx] : (f16)0.f;
    return;
  }
  idx -= 36864;
  if (idx < 147456) {  // Wdefp: [t][cc][ofr][lane][8] lane-linear A-frags
    int j = (int)(idx & 7);
    int ln = (int)((idx >> 3) & 63);
    int ofr = (int)((idx >> 9) & 7);
    int cc = (int)((idx >> 12) & 3);
    int t = (int)(idx >> 14);
    int o = ofr * 16 + (ln & 15);
    int c = cc * 32 + (ln >> 4) * 8 + j;
    Wdefp[idx] = (f16)wdef[(((size_t)o * 128 + c) * 3 + t / 3) * 3 + t % 3];
    return;
  }
  idx -= 147456;
  if (idx < 132096) { halo_zero(xP, idx); return; }
  idx -= 132096;
  if (idx < 132096) { halo_zero(refP, idx); return; }
  idx -= 132096;
  if (idx < 132096) { halo_zero(est1, idx); return; }
  idx -= 132096;
  if (idx < 132096) halo_zero(est2, idx);
}

// ---- implicit-GEMM 3x3 conv: M=128 (full row), N=64, BK=32, 4 waves ----
// R9-proven version (reg-staging, 3-buffer LDS, one barrier per stage).
// R10's B-direct-from-global variant regressed; reverted.
// XCD swizzle: blockIdx%8 = XCD owns a contiguous 32-row band.
template <int NKC>
__global__ __launch_bounds__(256, 2) void conv_k(const f16* __restrict__ src0,
                                                 const f16* __restrict__ src1,
                                                 const f16* __restrict__ Wp,
                                                 f16* __restrict__ dst) {
  constexpr int S = 3 * NKC;
  const int j = blockIdx.x;         // 0..511
  const int xcd = j & 7, ji = j >> 3;
  const int row = xcd * 32 + (ji & 31);  // XCD k: rows [32k, 32k+32)
  const int nb = ji >> 5;
  const int b = row >> 7, h = row & 127;
  __shared__ __align__(16) f16 As[3][130][32];     // 24.4 KB
  __shared__ __align__(16) f16 Bs[3][3][64][32];   // 36 KB  (total 60.4 KB, 2 blk/CU)
  const int tid = threadIdx.x;
  const int lane = tid & 63, wave = tid >> 6;
  const int l16 = lane & 15, quad = lane >> 4;
  const int wmB = wave * 32;  // wave tile: 32 px x 64 o
  f32x4 acc[2][4] = {};

  i32x4 ra0, ra1, ra2, rb0, rb1, rb2;  // staging regs (next stage in flight)

  auto stage_load = [&](int s) {  // issue global loads -> regs (non-blocking)
    int ky = s / NKC, cc = s % NKC;
    const f16* sp = (NKC == 8 && cc >= 4) ? src1 : src0;
    int c0 = (NKC == 8 ? (cc & 3) : cc) * 32;
    const f16* abase = sp + ((size_t)(b * 130 + h + ky) * 130) * 128 + c0;
    {
      int ch = tid;
      int xx = ch >> 2, g = ch & 3;
      ra0 = *(const i32x4*)(abase + (size_t)xx * 128 + ((g ^ ((xx >> 1) & 3)) << 3));
    }
    {
      int ch = 256 + tid;
      int xx = ch >> 2, g = ch & 3;
      ra1 = *(const i32x4*)(abase + (size_t)xx * 128 + ((g ^ ((xx >> 1) & 3)) << 3));
    }
    if (tid < 8) {
      int ch = 512 + tid;
      int xx = ch >> 2, g = ch & 3;
      ra2 = *(const i32x4*)(abase + (size_t)xx * 128 + ((g ^ ((xx >> 1) & 3)) << 3));
    }
    const f16* bbase = Wp + (size_t)((ky * NKC + cc) * 2 + nb) * (3 * 64 * 32);
    rb0 = *(const i32x4*)(bbase + (size_t)tid * 8);
    rb1 = *(const i32x4*)(bbase + (size_t)(256 + tid) * 8);
    rb2 = *(const i32x4*)(bbase + (size_t)(512 + tid) * 8);
  };
  auto stage_write = [&](int buf) {  // regs -> LDS (compiler inserts vmcnt wait)
    *(i32x4*)((char*)&As[buf][0][0] + tid * 16) = ra0;
    *(i32x4*)((char*)&As[buf][0][0] + (256 + tid) * 16) = ra1;
    if (tid < 8)
      *(i32x4*)((char*)&As[buf][0][0] + (512 + tid) * 16) = ra2;
    *(i32x4*)((char*)&Bs[buf][0][0][0] + tid * 16) = rb0;
    *(i32x4*)((char*)&Bs[buf][0][0][0] + (256 + tid) * 16) = rb1;
    *(i32x4*)((char*)&Bs[buf][0][0][0] + (512 + tid) * 16) = rb2;
  };

  stage_load(0);
  stage_write(0);          // waits the loads (reg deps), fills buf0
  stage_load(1);           // stage 1 in flight across the barrier
  __syncthreads();
  for (int s = 0; s < S; ++s) {
    const int buf = s % 3;
#pragma unroll
    for (int kx = 0; kx < 3; ++kx) {
      f16x8 bf[4];
#pragma unroll
      for (int j2 = 0; j2 < 4; ++j2) {
        int o = j2 * 16 + l16;
        bf[j2] = *(const f16x8*)&Bs[buf][kx][o][(quad ^ ((o >> 1) & 3)) << 3];
      }
#pragma unroll
      for (int i = 0; i < 2; ++i) {
        int xx = wmB + i * 16 + l16 + kx;
        f16x8 a = *(const f16x8*)&As[buf][xx][(quad ^ ((xx >> 1) & 3)) << 3];
#pragma unroll
        for (int j2 = 0; j2 < 4; ++j2)
          acc[i][j2] = __builtin_amdgcn_mfma_f32_16x16x32_f16(a, bf[j2], acc[i][j2], 0, 0, 0);
      }
    }
    if (s + 1 < S) stage_write((s + 1) % 3);
    if (s + 2 < S) stage_load(s + 2);
    __syncthreads();
  }
#pragma unroll
  for (int i = 0; i < 2; ++i)
#pragma unroll
    for (int j2 = 0; j2 < 4; ++j2) {
      int o = nb * 64 + j2 * 16 + l16;
#pragma unroll
      for (int rr = 0; rr < 4; ++rr) {
        int m = wmB + i * 16 + quad * 4 + rr;
        float v = fmaxf(acc[i][j2][rr], 0.f);
        dst[((size_t)(b * 130 + h + 1) * 130 + m + 1) * 128 + o] = (f16)v;
      }
    }
}

// ---- deform (merged offset conv), R11: 32 px/block -> grid 1024, 4 blk/CU.
// R10 counters: deform 57us, MfmaUtil 7%, Occupancy 19% -> latency-bound,
// needs TLP. LDS 33.4KB + launch_bounds(256,4) (VGPR<=128, af-dbuf dropped)
// doubles co-resident blocks. Gather remap 8 thr/px: half the per-thread
// gather chain; Ss write becomes 2-way banked (free) vs 4-way.
__global__ __launch_bounds__(256, 4) void deform_k(const f16* __restrict__ refP,
                                                   const f16* __restrict__ est2,
                                                   const f16* __restrict__ Woffp,
                                                   const f16* __restrict__ Wdefp,
                                                   float* __restrict__ out) {
  const int j = blockIdx.x;  // 0..1023
  const int xcd = j & 7, ji = j >> 3;     // ji 0..127
  const int row = xcd * 32 + (ji & 31);   // XCD band
  const int tile = ji >> 5;               // 0..3 (32-px window)
  const int b = row >> 7, h = row & 127;
  // phase A: As3 6528B + Bs3 18432B = 24960B; phase C: Ss 16384B (aliased)
  __shared__ __align__(16) char smem[24960];
  __shared__ __align__(16) float offs[32][32];  // 4 KB
  __shared__ int4 meta[9][32];                  // 4.5 KB
  f16 (*Ss)[32][128] = (f16(*)[32][128])smem;
  f16 (*As3)[34][32] = (f16(*)[34][32])smem;                 // 3 x 2176 B
  f16 (*Bs3)[3][32][32] = (f16(*)[3][32][32])(smem + 6528);  // 3 x 6144 B
  const int tid = threadIdx.x;
  const int lane = tid & 63, wave = tid >> 6;
  const int l16 = lane & 15, quad = lane >> 4;
  const int x0 = tile * 32;  // padded-col window base: cols x0 .. x0+33

  // ---- phase A: offset mini-conv M=32, 12 stages; waves 0-1 compute ----
  {
    i32x4 ra0, rb0, rb1;
    auto sl = [&](int s) {
      int ky = s >> 2, cc = s & 3;
      const f16* abase = est2 + (((size_t)(b * 130 + h + ky)) * 130 + x0) * 128 + cc * 32;
      if (tid < 136) {  // 34 px x 32 ch = 136 x 16B
        int xx = tid >> 2, g = tid & 3;
        ra0 = *(const i32x4*)(abase + (size_t)xx * 128 + ((g ^ ((xx >> 1) & 3)) << 3));
      }
      const f16* bbase = Woffp + (size_t)(ky * 4 + cc) * (3 * 32 * 32);
      rb0 = *(const i32x4*)(bbase + (size_t)tid * 8);
      if (tid < 128) rb1 = *(const i32x4*)(bbase + (size_t)(256 + tid) * 8);
    };
    auto sw = [&](int buf) {
      if (tid < 136)
        *(i32x4*)((char*)&As3[buf][0][0] + tid * 16) = ra0;
      *(i32x4*)((char*)&Bs3[buf][0][0][0] + tid * 16) = rb0;
      if (tid < 128)
        *(i32x4*)((char*)&Bs3[buf][0][0][0] + (256 + tid) * 16) = rb1;
    };
    f32x4 oacc[2] = {};
    sl(0); sw(0); sl(1);
    __syncthreads();
    for (int s = 0; s < 12; ++s) {
      const int buf = s % 3;
      if (wave < 2) {
#pragma unroll
        for (int kx = 0; kx < 3; ++kx) {
          f16x8 bf[2];
#pragma unroll
          for (int j2 = 0; j2 < 2; ++j2) {
            int o = j2 * 16 + l16;
            bf[j2] = *(const f16x8*)&Bs3[buf][kx][o][(quad ^ ((o >> 1) & 3)) << 3];
          }
          int xx = wave * 16 + l16 + kx;
          f16x8 a = *(const f16x8*)&As3[buf][xx][(quad ^ ((xx >> 1) & 3)) << 3];
#pragma unroll
          for (int j2 = 0; j2 < 2; ++j2)
            oacc[j2] = __builtin_amdgcn_mfma_f32_16x16x32_f16(a, bf[j2], oacc[j2], 0, 0, 0);
        }
      }
      if (s + 1 < 12) sw((s + 1) % 3);
      if (s + 2 < 12) sl(s + 2);
      __syncthreads();
    }
    if (wave < 2) {
#pragma unroll
      for (int j2 = 0; j2 < 2; ++j2)
#pragma unroll
        for (int rr = 0; rr < 4; ++rr)
          offs[wave * 16 + quad * 4 + rr][j2 * 16 + l16] = oacc[j2][rr];
    }
  }
  __syncthreads();  // offs ready; As3/Bs3 dead from here (Ss may overwrite)

  // ---- phase B: meta from offs (9 taps x 32 px) ----
  for (int e = tid; e < 288; e += 256) {
    int t = e >> 5, p = e & 31;
    int wg = tile * 32 + p;
    float dy = offs[p][2 * t], dx = offs[p][2 * t + 1];
    float py = (float)(h + t / 3 - 1) + dy;
    float px = (float)(wg + t % 3 - 1) + dx;
    float fy = floorf(py), fx = floorf(px);
    meta[t][p] = make_int4((int)fy, (int)fx, __float_as_int(py - fy), __float_as_int(px - fx));
  }

  const int sp_p = tid >> 3, sp_cg = tid & 7;  // 8 threads per px, 16 ch each
  f16x8 v00[2], v01[2], v10[2], v11[2];        // gather corners (16 ch)
  f16 h00, h01, h10, h11;

  auto sample_issue = [&](int t) {
    int4 mt = meta[t][sp_p];
    int yp = mt.x + 1, xp = mt.y + 1;  // padded coords
    float wy = __int_as_float(mt.z), wx = __int_as_float(mt.w);
    bool y0v = (unsigned)yp < 130u, y1v = (unsigned)(yp + 1) < 130u;
    bool x0v = (unsigned)xp < 130u, x1v = (unsigned)(xp + 1) < 130u;
    int cy0 = y0v ? yp : 0, cy1 = y1v ? yp + 1 : 0;
    int cx0 = x0v ? xp : 0, cx1 = x1v ? xp + 1 : 0;
    float u0 = (1.f - wy) * (y0v ? 1.f : 0.f), u1 = wy * (y1v ? 1.f : 0.f);
    float s0 = (1.f - wx) * (x0v ? 1.f : 0.f), s1 = wx * (x1v ? 1.f : 0.f);
    h00 = (f16)(u0 * s0); h01 = (f16)(u0 * s1);
    h10 = (f16)(u1 * s0); h11 = (f16)(u1 * s1);
    const size_t bb = (size_t)b * 130;
    const f16* p00 = refP + ((bb + cy0) * 130 + cx0) * 128 + sp_cg * 16;
    const f16* p01 = refP + ((bb + cy0) * 130 + cx1) * 128 + sp_cg * 16;
    const f16* p10 = refP + ((bb + cy1) * 130 + cx0) * 128 + sp_cg * 16;
    const f16* p11 = refP + ((bb + cy1) * 130 + cx1) * 128 + sp_cg * 16;
#pragma unroll
    for (int q = 0; q < 2; ++q) {
      v00[q] = *(const f16x8*)(p00 + q * 8);
      v01[q] = *(const f16x8*)(p01 + q * 8);
      v10[q] = *(const f16x8*)(p10 + q * 8);
      v11[q] = *(const f16x8*)(p11 + q * 8);
    }
  };
  auto sample_finish = [&](int buf) {
#pragma unroll
    for (int q = 0; q < 2; ++q) {
      f16x8 rb = v00[q] * h00 + v01[q] * h01 + v10[q] * h10 + v11[q] * h11;
      int c = sp_cg * 2 + q;  // 8-ch chunk index 0..15
      *(f16x8*)&Ss[buf][sp_p][(c ^ (sp_p & 7)) << 3] = rb;
    }
  };

  f32x4 acc[2][2] = {};
  __syncthreads();  // meta ready
  sample_issue(0);
  sample_finish(0);
  __syncthreads();
#pragma unroll
  for (int t = 0; t < 9; ++t) {
    f16x8 af[4][2];  // weights straight to A-frags (L2-hot)
#pragma unroll
    for (int cc = 0; cc < 4; ++cc)
#pragma unroll
      for (int i = 0; i < 2; ++i)
        af[cc][i] = *(const f16x8*)(Wdefp +
            ((((size_t)t * 4 + cc) * 8 + wave * 2 + i) * 64 + lane) * 8);
    if (t < 8) sample_issue(t + 1);  // gathers in flight during MFMAs
    const int buf = t & 1;
    __builtin_amdgcn_s_setprio(1);
#pragma unroll
    for (int cc = 0; cc < 4; ++cc) {
      f16x8 bf[2];
#pragma unroll
      for (int j2 = 0; j2 < 2; ++j2) {
        int p = j2 * 16 + l16;
        bf[j2] = *(const f16x8*)&Ss[buf][p][((cc * 4 + quad) ^ (p & 7)) << 3];
      }
#pragma unroll
      for (int i = 0; i < 2; ++i)
#pragma unroll
        for (int j2 = 0; j2 < 2; ++j2)
          acc[i][j2] = __builtin_amdgcn_mfma_f32_16x16x32_f16(af[cc][i], bf[j2], acc[i][j2], 0, 0, 0);
    }
    __builtin_amdgcn_s_setprio(0);
    if (t < 8) sample_finish((t + 1) & 1);
    __syncthreads();
  }
#pragma unroll
  for (int i = 0; i < 2; ++i)
#pragma unroll
    for (int rr = 0; rr < 4; ++rr) {
      int o = wave * 32 + i * 16 + quad * 4 + rr;
#pragma unroll
      for (int j2 = 0; j2 < 2; ++j2) {
        int wg = tile * 32 + j2 * 16 + l16;
        out[((size_t)(b * 128 + o) * 128 + h) * 128 + wg] = acc[i][j2][rr];
      }
    }
}

extern "C" void kernel_launch(void* const* d_in, const int* in_sizes, int n_in,
                              void* d_out, int out_size, void* d_ws, size_t ws_size,
                              hipStream_t stream) {
  const float* x = (const float*)d_in[0];
  const float* ref = (const float*)d_in[1];
  const float* w1 = (const float*)d_in[2];
  const float* w2 = (const float*)d_in[3];
  const float* woff = (const float*)d_in[4];
  const float* wdef = (const float*)d_in[5];
  float* out = (float*)d_out;
  char* ws = (char*)d_ws;
  f16* xP = (f16*)(ws + 0);              //  8,652,800
  f16* refP = (f16*)(ws + 8652800);      //  8,652,800
  f16* est1 = (f16*)(ws + 17305600);     //  8,652,800
  f16* est2 = (f16*)(ws + 25958400);     //  8,652,800
  f16* W1p = (f16*)(ws + 34611200);      //    589,824
  f16* W2p = (f16*)(ws + 35201024);      //    294,912
  f16* Woffp = (f16*)(ws + 35495936);    //     73,728
  f16* Wdefp = (f16*)(ws + 35569664);    //    294,912

  init_k<<<dim3(8608), 256, 0, stream>>>(x, ref, w1, w2, woff, wdef,
                                         W1p, W2p, Woffp, Wdefp, xP, refP, est1, est2);
  conv_k<8><<<dim3(512), 256, 0, stream>>>(xP, refP, W1p, est1);
  conv_k<4><<<dim3(512), 256, 0, stream>>>(est1, est1, W2p, est2);
  deform_k<<<dim3(1024), 256, 0, stream>>>(refP, est2, Woffp, Wdefp, out);
}